// Round 4
// baseline (361.273 us; speedup 1.0000x reference)
//
#include <hip/hip_runtime.h>

// DenseDilatedKnnGraphDGL: B=64, C=256, N=1024, layer_idx=8 -> dilation=3, k=9, k_d=27
// out[0:589824]       = src_d (int32): rank-{0,3,..,24} neighbor index + b*N
// out[589824:1179648] = dst_d (int32): j/9
//
// R4 changes vs R3:
//  - knn: per-lane insertion top-8 during GEMM (kills the 64-reg kk array ->
//    occupancy), distributed 8/lane pair-based keep-16 cross-lane merge
//    (fewer VALU+DS), fully parallel rank-based final merge (kills the
//    serial 25-iter tail), __launch_bounds__(256,4).
//  - trans: LDS-staged transpose -> coalesced global reads AND writes.

typedef __bf16 bf16x8 __attribute__((ext_vector_type(8)));
typedef float  f32x4  __attribute__((ext_vector_type(4)));
typedef unsigned int u32;

#define B_   64
#define C_   256
#define N_   1024
#define NSRC (B_ * N_ * 9)   // 589824

__device__ __forceinline__ u32 umin_(u32 a, u32 b) { return a < b ? a : b; }
__device__ __forceinline__ u32 umax_(u32 a, u32 b) { return a > b ? a : b; }

// ---------------------------------------------------------------------------
// Kernel 1: transpose + fp32->bf16 + row norms, LDS-staged for coalescing.
// grid 1024 = 64 b x 16 row-chunks of 64; block 256 (4 waves).
// Phase A: lane owns column n=n0+lane, wave w covers c in [64w,64w+64);
//          packs bf16 pairs, stores to T[lane-as-row][c-pair] (stride 129).
// Phase B: thread (rr=tid>>2, p=tid&3) reads row rr's 32 u32 for quarter p,
//          stores 128B contiguous to XT -> coalesced 1KB/instr.
__global__ __launch_bounds__(256, 2) void trans_kernel(const float* __restrict__ X,
                                                       unsigned short* __restrict__ XT,
                                                       float* __restrict__ NRM) {
    __shared__ u32 T[64][129];
    __shared__ float part[64][5];
    const int tid  = threadIdx.x;
    const int lane = tid & 63;
    const int w    = tid >> 6;
    const int b    = blockIdx.x >> 4;
    const int n0   = (blockIdx.x & 15) * 64;

    const float* __restrict__ xb = X + ((size_t)b * C_ + w * 64) * N_ + n0 + lane;
    float nsq = 0.f;
#pragma unroll
    for (int j = 0; j < 32; ++j) {
        float f0 = xb[(size_t)(2 * j) * N_];
        float f1 = xb[(size_t)(2 * j + 1) * N_];
        nsq = fmaf(f0, f0, fmaf(f1, f1, nsq));
        u32 u0 = __float_as_uint(f0), u1 = __float_as_uint(f1);
        u32 b0 = (u0 + 0x7FFFu + ((u0 >> 16) & 1u)) >> 16;   // RNE to bf16
        u32 b1 = (u1 + 0x7FFFu + ((u1 >> 16) & 1u)) >> 16;
        T[lane][w * 32 + j] = b0 | (b1 << 16);
    }
    part[lane][w] = nsq;
    __syncthreads();

    const int rr = tid >> 2, p = tid & 3;
    u32 tmp[32];
#pragma unroll
    for (int j = 0; j < 32; ++j) tmp[j] = T[rr][p * 32 + j];
    uint4* dst = (uint4*)(XT + ((size_t)b * N_ + n0 + rr) * C_ + p * 64);
#pragma unroll
    for (int j = 0; j < 8; ++j)
        dst[j] = make_uint4(tmp[4 * j], tmp[4 * j + 1], tmp[4 * j + 2], tmp[4 * j + 3]);

    if (tid < 64)
        NRM[b * N_ + n0 + tid] = part[tid][0] + part[tid][1] + part[tid][2] + part[tid][3];
}

// ---------------------------------------------------------------------------
// bitonic-merge of a bitonic 8-seq in regs -> ascending (phases j=4,2,1)
#define SORT8(v)                                                              \
    do {                                                                      \
        u32 mn, mx;                                                           \
        mn = umin_(v[0], v[4]); mx = umax_(v[0], v[4]); v[0] = mn; v[4] = mx; \
        mn = umin_(v[1], v[5]); mx = umax_(v[1], v[5]); v[1] = mn; v[5] = mx; \
        mn = umin_(v[2], v[6]); mx = umax_(v[2], v[6]); v[2] = mn; v[6] = mx; \
        mn = umin_(v[3], v[7]); mx = umax_(v[3], v[7]); v[3] = mn; v[7] = mx; \
        mn = umin_(v[0], v[2]); mx = umax_(v[0], v[2]); v[0] = mn; v[2] = mx; \
        mn = umin_(v[1], v[3]); mx = umax_(v[1], v[3]); v[1] = mn; v[3] = mx; \
        mn = umin_(v[4], v[6]); mx = umax_(v[4], v[6]); v[4] = mn; v[6] = mx; \
        mn = umin_(v[5], v[7]); mx = umax_(v[5], v[7]); v[5] = mn; v[7] = mx; \
        mn = umin_(v[0], v[1]); mx = umax_(v[0], v[1]); v[0] = mn; v[1] = mx; \
        mn = umin_(v[2], v[3]); mx = umax_(v[2], v[3]); v[2] = mn; v[3] = mx; \
        mn = umin_(v[4], v[5]); mx = umax_(v[4], v[5]); v[4] = mn; v[5] = mx; \
        mn = umin_(v[6], v[7]); mx = umax_(v[6], v[7]); v[6] = mn; v[7] = mx; \
    } while (0)

// Kernel 2: MFMA distances + top-k selection. grid 4096; block 256 (4 waves).
__global__ __launch_bounds__(256, 4) void knn_mfma_kernel(const unsigned short* __restrict__ XT,
                                                          const float* __restrict__ NRM,
                                                          int* __restrict__ out) {
    __shared__ u32 lists[16 * 64];   // [row_local][wave*16 + slot]

    const int tid  = threadIdx.x;
    const int lane = tid & 63;
    const int w    = tid >> 6;

    const int bi   = blockIdx.x;
    const int jj   = bi >> 3;
    const int b    = (bi & 7) + 8 * (jj >> 6);   // batch-locality swizzle (mod-8)
    const int n0   = (jj & 63) * 16;

    const int lrow = lane & 15;
    const int lk   = (lane >> 4) * 8;
    const int g    = lane >> 4;
    const bool odd = lane & 1;

    const unsigned short* xtb = XT + (size_t)b * N_ * C_;

    // A fragments (16 queries, full K=256) in registers
    bf16x8 afr[8];
    {
        const unsigned short* ap = xtb + (n0 + lrow) * C_ + lk;
#pragma unroll
        for (int kc = 0; kc < 8; ++kc)
            afr[kc] = *(const bf16x8*)(ap + kc * 32);
    }

    const int m_base = w * 256;
    const float* nrmb = NRM + b * N_;

    // per-round per-lane sorted top-8 lists (ascending)
    u32 L[4][8];
#pragma unroll
    for (int r = 0; r < 4; ++r)
#pragma unroll
        for (int i = 0; i < 8; ++i) L[r][i] = 0xFFFFFFFFu;

#pragma unroll
    for (int t = 0; t < 16; ++t) {
        const int m0 = m_base + t * 16;
        const unsigned short* bp = xtb + (m0 + lrow) * C_ + lk;
        f32x4 acc = {0.f, 0.f, 0.f, 0.f};
#pragma unroll
        for (int kc = 0; kc < 8; ++kc) {
            bf16x8 bfr = *(const bf16x8*)(bp + kc * 32);
            acc = __builtin_amdgcn_mfma_f32_16x16x32_bf16(afr[kc], bfr, acc, 0, 0, 0);
        }
        const int m = m0 + lrow;
        const float nm = nrmb[m];
#pragma unroll
        for (int r = 0; r < 4; ++r) {
            float f = fmaf(-2.f, acc[r], nm);              // d2 minus row-const
            u32 u = __float_as_uint(f);
            u = u ^ ((u32)((int)u >> 31) | 0x80000000u);   // monotonic float->uint
            u32 cur = (u & 0xFFFFFC00u) | (u32)m;          // index in low 10 bits
            // insertion into sorted-8 (keep smallest 8)
#pragma unroll
            for (int i = 0; i < 8; ++i) {
                u32 lo = umin_(L[r][i], cur);
                u32 hi = umax_(L[r][i], cur);
                L[r][i] = lo; cur = hi;
            }
        }
    }

    // ---- cross-lane selection: round r -> group g's row is 4g+r.
    // Distributed lists: after stage 1, even lane of each pair holds ranks 0-7
    // ascending, odd lane ranks 8-15 ascending.
#pragma unroll
    for (int r = 0; r < 4; ++r) {
        u32 v[8], t1[8];
#pragma unroll
        for (int i = 0; i < 8; ++i) v[i] = L[r][i];

        // stage 1: pair formation (lanes l, l^1) -- keep all 16
#pragma unroll
        for (int i = 0; i < 8; ++i) t1[i] = __shfl_xor(v[i], 1);
#pragma unroll
        for (int i = 0; i < 8; ++i) {
            u32 mn = umin_(v[i], t1[7 - i]);
            u32 mx = umax_(v[i], t1[7 - i]);
            v[i] = odd ? mx : mn;
        }
        SORT8(v);

        // stages: pair-vs-pair keep-16 at pair distance D = 2,4,8
#pragma unroll
        for (int s = 0; s < 3; ++s) {
            const int mask = (2 << s) | 1;   // 3, 5, 9
#pragma unroll
            for (int i = 0; i < 8; ++i) t1[i] = __shfl_xor(v[i], mask);
#pragma unroll
            for (int i = 0; i < 8; ++i) v[i] = umin_(v[i], t1[7 - i]);  // keep-16 (bitonic)
            // merge-16 phase j=8 (cross parity), then in-lane j=4,2,1
#pragma unroll
            for (int i = 0; i < 8; ++i) t1[i] = __shfl_xor(v[i], 1);
#pragma unroll
            for (int i = 0; i < 8; ++i)
                v[i] = odd ? umax_(v[i], t1[i]) : umin_(v[i], t1[i]);
            SORT8(v);
        }

        // pair 0 of each group writes the group's sorted-16
        if ((lane & 15) < 2) {
            const int base = (4 * g + r) * 64 + w * 16 + (odd ? 8 : 0);
#pragma unroll
            for (int i = 0; i < 8; ++i) lists[base + i] = v[i];
        }
    }
    __syncthreads();

    // ---- final merge: parallel rank computation. thread (row=tid>>4, q=tid&15)
    // handles candidate q of each of the 4 sorted lists; rank = q + sum of
    // binary-search counts in the other 3 lists. Keys unique -> ranks unique.
    int* out_src = out;
    int* out_dst = out + NSRC;
    {
        const int row = tid >> 4;
        const int q   = tid & 15;
        const u32* Ls = &lists[row * 64];
        const int obase = (b * N_ + n0 + row) * 9;
#pragma unroll
        for (int jl = 0; jl < 4; ++jl) {
            const u32 val = Ls[jl * 16 + q];
            int rank = q;
#pragma unroll
            for (int jp = 0; jp < 4; ++jp) {
                if (jp == jl) continue;
                const u32* Lp = Ls + jp * 16;
                int pos = 0;
                pos += (Lp[pos + 7] < val) ? 8 : 0;
                pos += (Lp[pos + 3] < val) ? 4 : 0;
                pos += (Lp[pos + 1] < val) ? 2 : 0;
                pos += (Lp[pos]     < val) ? 1 : 0;
                rank += pos;
            }
            if (rank < 25 && (rank % 3) == 0)
                out_src[obase + rank / 3] = (b << 10) | (int)(val & 1023u);
        }
    }

    const int jbase = (b * N_ + n0) * 9;
    if (tid < 16 * 9) out_dst[jbase + tid] = (jbase + tid) / 9;
}

// ---------------------------------------------------------------------------
// Fallback (R1 kernel) if workspace is too small for XT+NRM
__global__ __launch_bounds__(256, 2) void knn_kernel(const float* __restrict__ X,
                                                     int* __restrict__ out) {
    __shared__ float smem[16 * N_];
    const int tid = threadIdx.x;
    const int b  = blockIdx.x >> 6;
    const int n0 = (blockIdx.x & 63) * 16;
    const float* __restrict__ xb = X + (size_t)b * C_ * N_;
#pragma unroll
    for (int i = 0; i < 16; ++i) {
        int f = tid + i * 256;
        int c = f >> 4, qq = f & 15;
        smem[f] = xb[c * N_ + n0 + qq];
    }
    __syncthreads();
    float acc[16][4];
#pragma unroll
    for (int q = 0; q < 16; ++q) { acc[q][0] = acc[q][1] = acc[q][2] = acc[q][3] = 0.f; }
    float nrm[4] = {0.f, 0.f, 0.f, 0.f};
    for (int c = 0; c < C_; ++c) {
        const float* __restrict__ xc = xb + c * N_;
        float bv0 = xc[tid], bv1 = xc[tid + 256], bv2 = xc[tid + 512], bv3 = xc[tid + 768];
        const float4* A4 = reinterpret_cast<const float4*>(smem + c * 16);
        float4 a0 = A4[0], a1 = A4[1], a2 = A4[2], a3 = A4[3];
        float aq[16] = {a0.x, a0.y, a0.z, a0.w, a1.x, a1.y, a1.z, a1.w,
                        a2.x, a2.y, a2.z, a2.w, a3.x, a3.y, a3.z, a3.w};
#pragma unroll
        for (int q = 0; q < 16; ++q) {
            acc[q][0] = fmaf(aq[q], bv0, acc[q][0]);
            acc[q][1] = fmaf(aq[q], bv1, acc[q][1]);
            acc[q][2] = fmaf(aq[q], bv2, acc[q][2]);
            acc[q][3] = fmaf(aq[q], bv3, acc[q][3]);
        }
        nrm[0] = fmaf(bv0, bv0, nrm[0]); nrm[1] = fmaf(bv1, bv1, nrm[1]);
        nrm[2] = fmaf(bv2, bv2, nrm[2]); nrm[3] = fmaf(bv3, bv3, nrm[3]);
    }
    __syncthreads();
#pragma unroll
    for (int q = 0; q < 16; ++q) {
        smem[q * N_ + tid]       = nrm[0] - 2.f * acc[q][0];
        smem[q * N_ + tid + 256] = nrm[1] - 2.f * acc[q][1];
        smem[q * N_ + tid + 512] = nrm[2] - 2.f * acc[q][2];
        smem[q * N_ + tid + 768] = nrm[3] - 2.f * acc[q][3];
    }
    __syncthreads();
    const int lane = tid & 63;
    const int w    = tid >> 6;
    int* out_src = out;
    int* out_dst = out + NSRC;
    for (int q = w; q < 16; q += 4) {
        float v[16];
#pragma unroll
        for (int i = 0; i < 16; ++i) v[i] = smem[q * N_ + lane + i * 64];
        float lv = v[0]; int ls = 0;
#pragma unroll
        for (int i = 1; i < 16; ++i) { if (v[i] < lv) { lv = v[i]; ls = i; } }
        int lm = lane + (ls << 6);
        const int obase = (b * N_ + n0 + q) * 9;
#pragma unroll
        for (int r = 0; r < 25; ++r) {
            float bv = lv; int bm = lm;
#pragma unroll
            for (int off = 32; off >= 1; off >>= 1) {
                float ov = __shfl_xor(bv, off);
                int   om = __shfl_xor(bm, off);
                if (ov < bv || (ov == bv && om < bm)) { bv = ov; bm = om; }
            }
            if ((r % 3) == 0 && lane == 0) out_src[obase + r / 3] = b * N_ + bm;
            if (bm == lm) {
#pragma unroll
                for (int i = 0; i < 16; ++i) { if (i == ls) v[i] = 3.4e38f; }
                lv = v[0]; ls = 0;
#pragma unroll
                for (int i = 1; i < 16; ++i) { if (v[i] < lv) { lv = v[i]; ls = i; } }
                lm = lane + (ls << 6);
            }
        }
    }
    const int jbase = (b * N_ + n0) * 9;
    if (tid < 16 * 9) out_dst[jbase + tid] = (jbase + tid) / 9;
}

extern "C" void kernel_launch(void* const* d_in, const int* in_sizes, int n_in,
                              void* d_out, int out_size, void* d_ws, size_t ws_size,
                              hipStream_t stream) {
    (void)in_sizes; (void)n_in; (void)out_size;
    const float* X = (const float*)d_in[0];
    int* out = (int*)d_out;
    const size_t xt_bytes  = (size_t)B_ * N_ * C_ * 2;   // 33,554,432
    const size_t nrm_bytes = (size_t)B_ * N_ * 4;        // 262,144
    if (ws_size >= xt_bytes + nrm_bytes) {
        unsigned short* XT = (unsigned short*)d_ws;
        float* NRM = (float*)((char*)d_ws + xt_bytes);
        trans_kernel<<<dim3(B_ * 16), dim3(256), 0, stream>>>(X, XT, NRM);
        knn_mfma_kernel<<<dim3(B_ * 64), dim3(256), 0, stream>>>(XT, NRM, out);
    } else {
        knn_kernel<<<dim3(B_ * 64), dim3(256), 0, stream>>>(X, out);
    }
}